// Round 2
// baseline (121.943 us; speedup 1.0000x reference)
//
#include <hip/hip_runtime.h>
#include <hip/hip_fp16.h>
#include <math.h>

// RipsH1: deaths[i] = ||points[verts0[i,0]] - points[verts0[i,1]]||  (E0 rows)
//         dgm1[i,:] = ||points[verts1[i,{0,2}]] - points[verts1[i,{1,3}]]||  (E1 rows)
// Output flat: deaths (E0 floats) then dgm1 row-major (2*E1 floats).
//
// Round-3 theory: the kernel is L2-scatter-request-rate bound (8.13M random
// 16B gathers; ~26.5us ideal channel rate, measured 44.5us = 65% eff).
// Levers this round (efficiency, not count — count is irreducible):
//  (a) 8 gathers in flight per thread (2 verts1 rows/thread) -> deeper queues,
//  (b) XCD-contiguous block swizzle -> each XCD L2 sees only its verts/out
//      slice + the 1MB table; verts become L2-resident across iterations,
//  (c) 32B/thread coalesced index loads, NT on all streaming accesses.

typedef int v4i __attribute__((ext_vector_type(4)));
typedef int v2i __attribute__((ext_vector_type(2)));

__global__ __launch_bounds__(256) void cvt_kernel(
    const float* __restrict__ pts, __half* __restrict__ out, int n4) {
    int i = blockIdx.x * blockDim.x + threadIdx.x;
    if (i < n4) {
        float4 f = ((const float4*)pts)[i];
        __half2 h0 = __floats2half2_rn(f.x, f.y);
        __half2 h1 = __floats2half2_rn(f.z, f.w);
        ((__half2*)out)[2 * i]     = h0;
        ((__half2*)out)[2 * i + 1] = h1;
    }
}

__device__ __forceinline__ float2 u2f2(unsigned u) {
    __half2 h = *reinterpret_cast<__half2*>(&u);
    return __half22float2(h);
}

// distance from two pre-gathered fp16x8 points
__device__ __forceinline__ float dist8v(uint4 a, uint4 b) {
    float2 ax = u2f2(a.x), ay = u2f2(a.y), az = u2f2(a.z), aw = u2f2(a.w);
    float2 bx = u2f2(b.x), by = u2f2(b.y), bz = u2f2(b.z), bw = u2f2(b.w);
    float d0 = ax.x - bx.x, d1 = ax.y - bx.y;
    float d2 = ay.x - by.x, d3 = ay.y - by.y;
    float d4 = az.x - bz.x, d5 = az.y - bz.y;
    float d6 = aw.x - bw.x, d7 = aw.y - bw.y;
    float s = d0 * d0 + d1 * d1 + d2 * d2 + d3 * d3
            + d4 * d4 + d5 * d5 + d6 * d6 + d7 * d7;
    return sqrtf(s);
}

// Bijective XCD-contiguous swizzle (m204 form): round-robin dispatch position
// (xcd = b%8) is remapped to a contiguous chunk of the grid per XCD.
__device__ __forceinline__ int xcd_swizzle(int b, int nwg) {
    int q = nwg >> 3, r = nwg & 7;
    int xcd = b & 7, off = b >> 3;
    int base = (xcd < r) ? xcd * (q + 1) : r * (q + 1) + (xcd - r) * q;
    return base + off;
}

// One thread = TWO verts1 rows (4 distances, 8 gathers in flight).
__global__ __launch_bounds__(256) void rips_kernel_h8(
    const __half* __restrict__ points16,
    const int* __restrict__ verts0,
    const int* __restrict__ verts1,
    float* __restrict__ out,
    int e0, int e1) {
    int sb = xcd_swizzle(blockIdx.x, gridDim.x);
    int tid = sb * blockDim.x + threadIdx.x;
    const uint4* p = (const uint4*)points16;
    int npair = e1 >> 1;           // verts1 row-pairs
    int rem   = e1 & 1;            // leftover odd row (none for this problem)
    if (tid < npair) {
        const v4i* v1 = (const v4i*)verts1;
        v4i va = __builtin_nontemporal_load(v1 + 2 * tid);
        v4i vb = __builtin_nontemporal_load(v1 + 2 * tid + 1);
        // 8 independent gathers issued back-to-back
        uint4 g0 = p[va.x];
        uint4 g1 = p[va.y];
        uint4 g2 = p[va.z];
        uint4 g3 = p[va.w];
        uint4 g4 = p[vb.x];
        uint4 g5 = p[vb.y];
        uint4 g6 = p[vb.z];
        uint4 g7 = p[vb.w];
        float r0 = dist8v(g0, g1);
        float r1 = dist8v(g2, g3);
        float r2 = dist8v(g4, g5);
        float r3 = dist8v(g6, g7);
        float* o = out + e0 + 4 * tid;   // odd e0 -> only 4B alignment: scalar stores
        __builtin_nontemporal_store(r0, o);
        __builtin_nontemporal_store(r1, o + 1);
        __builtin_nontemporal_store(r2, o + 2);
        __builtin_nontemporal_store(r3, o + 3);
    } else {
        int j = tid - npair;
        if (j < rem) {
            // odd trailing verts1 row
            int row = e1 - 1;
            v2i v = __builtin_nontemporal_load((const v2i*)verts1 + 2 * row);
            v2i w = __builtin_nontemporal_load((const v2i*)verts1 + 2 * row + 1);
            float r0 = dist8v(p[v.x], p[v.y]);
            float r1 = dist8v(p[w.x], p[w.y]);
            __builtin_nontemporal_store(r0, out + e0 + 2 * row);
            __builtin_nontemporal_store(r1, out + e0 + 2 * row + 1);
        } else {
            j -= rem;
            if (j < e0) {
                v2i v = __builtin_nontemporal_load((const v2i*)verts0 + j);
                float r = dist8v(p[v.x], p[v.y]);
                __builtin_nontemporal_store(r, out + j);
            }
        }
    }
}

// Fallback (f32 gathers) in case ws is too small for the fp16 table.
__device__ __forceinline__ float dist8f(const float4* __restrict__ p, int ia, int ib) {
    float4 a0 = p[2 * ia], a1 = p[2 * ia + 1];
    float4 b0 = p[2 * ib], b1 = p[2 * ib + 1];
    float d0 = a0.x - b0.x, d1 = a0.y - b0.y, d2 = a0.z - b0.z, d3 = a0.w - b0.w;
    float d4 = a1.x - b1.x, d5 = a1.y - b1.y, d6 = a1.z - b1.z, d7 = a1.w - b1.w;
    return sqrtf(d0*d0 + d1*d1 + d2*d2 + d3*d3 + d4*d4 + d5*d5 + d6*d6 + d7*d7);
}

__global__ __launch_bounds__(256) void rips_kernel_f2(
    const float* __restrict__ points,
    const int* __restrict__ verts0,
    const int* __restrict__ verts1,
    float* __restrict__ out,
    int e0, int e1) {
    int tid = blockIdx.x * blockDim.x + threadIdx.x;
    const float4* p = (const float4*)points;
    int n1 = 2 * e1;
    if (tid < n1) {
        v2i v = __builtin_nontemporal_load((const v2i*)verts1 + tid);
        float r = dist8f(p, v.x, v.y);
        __builtin_nontemporal_store(r, out + e0 + tid);
    } else {
        int j = tid - n1;
        if (j < e0) {
            v2i v = __builtin_nontemporal_load((const v2i*)verts0 + j);
            float r = dist8f(p, v.x, v.y);
            __builtin_nontemporal_store(r, out + j);
        }
    }
}

extern "C" void kernel_launch(void* const* d_in, const int* in_sizes, int n_in,
                              void* d_out, int out_size, void* d_ws, size_t ws_size,
                              hipStream_t stream) {
    const float* points = (const float*)d_in[0];
    const int* verts0   = (const int*)d_in[1];
    const int* verts1   = (const int*)d_in[2];
    float* out = (float*)d_out;

    int npts_flat = in_sizes[0];       // 65536*8 floats
    int e0 = in_sizes[1] / 2;          // 65535
    int e1 = in_sizes[2] / 4;          // 2000000

    size_t fp16_bytes = (size_t)npts_flat * sizeof(__half);
    if (ws_size >= fp16_bytes) {
        __half* p16 = (__half*)d_ws;
        int n4 = npts_flat / 4;
        cvt_kernel<<<(n4 + 255) / 256, 256, 0, stream>>>(points, p16, n4);

        int npair = e1 / 2;
        int rem   = e1 & 1;
        int total = npair + rem + e0;   // threads
        int block = 256;
        int grid = (total + block - 1) / block;
        rips_kernel_h8<<<grid, block, 0, stream>>>(p16, verts0, verts1, out, e0, e1);
    } else {
        int total = 2 * e1 + e0;
        int block = 256;
        int grid = (total + block - 1) / block;
        rips_kernel_f2<<<grid, block, 0, stream>>>(points, verts0, verts1, out, e0, e1);
    }
}

// Round 3
// 121.543 us; speedup vs baseline: 1.0033x; 1.0033x over previous
//
#include <hip/hip_runtime.h>
#include <hip/hip_fp16.h>
#include <math.h>

// RipsH1: deaths[i] = ||points[verts0[i,0]] - points[verts0[i,1]]||  (E0 rows)
//         dgm1[i,:] = ||points[verts1[i,{0,2}]] - points[verts1[i,{1,3}]]||  (E1 rows)
// Output flat: deaths (E0 floats) then dgm1 row-major (2*E1 floats).
//
// Round-4 discriminating experiment: the rips kernel is stuck at 44-45us
// across 3 structurally different versions (MLP depth / NT streams / XCD
// swizzle all neutral). Per-CU effective rate = ~218 cyc per wave64 gather
// == L2-hit latency => candidate wall is the per-CU L1 pending-miss pool
// (~64) serializing at L2 latency. Test: gather with `sc0` (bypass L1
// allocation, still L2-cached). If neutral, the wall is the L2 channel
// request rate (26.5us ideal, ~60% eff) and we are at the roofline.

typedef int v4i __attribute__((ext_vector_type(4)));
typedef int v2i __attribute__((ext_vector_type(2)));

__global__ __launch_bounds__(256) void cvt_kernel(
    const float* __restrict__ pts, __half* __restrict__ out, int n4) {
    int i = blockIdx.x * blockDim.x + threadIdx.x;
    if (i < n4) {
        float4 f = ((const float4*)pts)[i];
        __half2 h0 = __floats2half2_rn(f.x, f.y);
        __half2 h1 = __floats2half2_rn(f.z, f.w);
        ((__half2*)out)[2 * i]     = h0;
        ((__half2*)out)[2 * i + 1] = h1;
    }
}

__device__ __forceinline__ float2 u2f2(unsigned u) {
    __half2 h = *reinterpret_cast<__half2*>(&u);
    return __half22float2(h);
}

// 16B gather that bypasses L1 allocation (sc0 = device-coherent load on
// gfx940+, the old `glc`). Data still hits/fills L2. NOTE: consumer must
// wait vmcnt manually — see wait_all_gathers().
__device__ __forceinline__ uint4 ld_sc0(const uint4* a) {
    uint4 d;
    asm volatile("global_load_dwordx4 %0, %1, off sc0" : "=&v"(d) : "v"(a));
    return d;
}

__device__ __forceinline__ void wait_all_gathers() {
    asm volatile("s_waitcnt vmcnt(0)" ::: "memory");
    __builtin_amdgcn_sched_barrier(0);   // rule #18: stop hoisting consumers
}

// distance from two pre-gathered fp16x8 points
__device__ __forceinline__ float dist8v(uint4 a, uint4 b) {
    float2 ax = u2f2(a.x), ay = u2f2(a.y), az = u2f2(a.z), aw = u2f2(a.w);
    float2 bx = u2f2(b.x), by = u2f2(b.y), bz = u2f2(b.z), bw = u2f2(b.w);
    float d0 = ax.x - bx.x, d1 = ax.y - bx.y;
    float d2 = ay.x - by.x, d3 = ay.y - by.y;
    float d4 = az.x - bz.x, d5 = az.y - bz.y;
    float d6 = aw.x - bw.x, d7 = aw.y - bw.y;
    float s = d0 * d0 + d1 * d1 + d2 * d2 + d3 * d3
            + d4 * d4 + d5 * d5 + d6 * d6 + d7 * d7;
    return sqrtf(s);
}

// One thread = TWO verts1 rows (4 distances, 8 sc0 gathers in flight).
__global__ __launch_bounds__(256) void rips_kernel_sc0(
    const __half* __restrict__ points16,
    const int* __restrict__ verts0,
    const int* __restrict__ verts1,
    float* __restrict__ out,
    int e0, int e1) {
    int tid = blockIdx.x * blockDim.x + threadIdx.x;
    const uint4* p = (const uint4*)points16;
    int npair = e1 >> 1;           // verts1 row-pairs
    int rem   = e1 & 1;            // leftover odd row (0 for this problem)
    if (tid < npair) {
        const v4i* v1 = (const v4i*)verts1;
        v4i va = __builtin_nontemporal_load(v1 + 2 * tid);
        v4i vb = __builtin_nontemporal_load(v1 + 2 * tid + 1);
        // 8 independent L1-bypass gathers issued back-to-back
        uint4 g0 = ld_sc0(p + va.x);
        uint4 g1 = ld_sc0(p + va.y);
        uint4 g2 = ld_sc0(p + va.z);
        uint4 g3 = ld_sc0(p + va.w);
        uint4 g4 = ld_sc0(p + vb.x);
        uint4 g5 = ld_sc0(p + vb.y);
        uint4 g6 = ld_sc0(p + vb.z);
        uint4 g7 = ld_sc0(p + vb.w);
        wait_all_gathers();
        float r0 = dist8v(g0, g1);
        float r1 = dist8v(g2, g3);
        float r2 = dist8v(g4, g5);
        float r3 = dist8v(g6, g7);
        float* o = out + e0 + 4 * tid;   // odd e0 -> only 4B alignment: scalar stores
        __builtin_nontemporal_store(r0, o);
        __builtin_nontemporal_store(r1, o + 1);
        __builtin_nontemporal_store(r2, o + 2);
        __builtin_nontemporal_store(r3, o + 3);
    } else {
        int j = tid - npair;
        if (j < rem) {
            // odd trailing verts1 row
            int row = e1 - 1;
            v2i v = __builtin_nontemporal_load((const v2i*)verts1 + 2 * row);
            v2i w = __builtin_nontemporal_load((const v2i*)verts1 + 2 * row + 1);
            uint4 g0 = ld_sc0(p + v.x);
            uint4 g1 = ld_sc0(p + v.y);
            uint4 g2 = ld_sc0(p + w.x);
            uint4 g3 = ld_sc0(p + w.y);
            wait_all_gathers();
            __builtin_nontemporal_store(dist8v(g0, g1), out + e0 + 2 * row);
            __builtin_nontemporal_store(dist8v(g2, g3), out + e0 + 2 * row + 1);
        } else {
            j -= rem;
            if (j < e0) {
                v2i v = __builtin_nontemporal_load((const v2i*)verts0 + j);
                uint4 g0 = ld_sc0(p + v.x);
                uint4 g1 = ld_sc0(p + v.y);
                wait_all_gathers();
                __builtin_nontemporal_store(dist8v(g0, g1), out + j);
            }
        }
    }
}

// Fallback (f32 gathers) in case ws is too small for the fp16 table.
__device__ __forceinline__ float dist8f(const float4* __restrict__ p, int ia, int ib) {
    float4 a0 = p[2 * ia], a1 = p[2 * ia + 1];
    float4 b0 = p[2 * ib], b1 = p[2 * ib + 1];
    float d0 = a0.x - b0.x, d1 = a0.y - b0.y, d2 = a0.z - b0.z, d3 = a0.w - b0.w;
    float d4 = a1.x - b1.x, d5 = a1.y - b1.y, d6 = a1.z - b1.z, d7 = a1.w - b1.w;
    return sqrtf(d0*d0 + d1*d1 + d2*d2 + d3*d3 + d4*d4 + d5*d5 + d6*d6 + d7*d7);
}

__global__ __launch_bounds__(256) void rips_kernel_f2(
    const float* __restrict__ points,
    const int* __restrict__ verts0,
    const int* __restrict__ verts1,
    float* __restrict__ out,
    int e0, int e1) {
    int tid = blockIdx.x * blockDim.x + threadIdx.x;
    const float4* p = (const float4*)points;
    int n1 = 2 * e1;
    if (tid < n1) {
        v2i v = __builtin_nontemporal_load((const v2i*)verts1 + tid);
        float r = dist8f(p, v.x, v.y);
        __builtin_nontemporal_store(r, out + e0 + tid);
    } else {
        int j = tid - n1;
        if (j < e0) {
            v2i v = __builtin_nontemporal_load((const v2i*)verts0 + j);
            float r = dist8f(p, v.x, v.y);
            __builtin_nontemporal_store(r, out + j);
        }
    }
}

extern "C" void kernel_launch(void* const* d_in, const int* in_sizes, int n_in,
                              void* d_out, int out_size, void* d_ws, size_t ws_size,
                              hipStream_t stream) {
    const float* points = (const float*)d_in[0];
    const int* verts0   = (const int*)d_in[1];
    const int* verts1   = (const int*)d_in[2];
    float* out = (float*)d_out;

    int npts_flat = in_sizes[0];       // 65536*8 floats
    int e0 = in_sizes[1] / 2;          // 65535
    int e1 = in_sizes[2] / 4;          // 2000000

    size_t fp16_bytes = (size_t)npts_flat * sizeof(__half);
    if (ws_size >= fp16_bytes) {
        __half* p16 = (__half*)d_ws;
        int n4 = npts_flat / 4;
        cvt_kernel<<<(n4 + 255) / 256, 256, 0, stream>>>(points, p16, n4);

        int npair = e1 / 2;
        int rem   = e1 & 1;
        int total = npair + rem + e0;   // threads
        int block = 256;
        int grid = (total + block - 1) / block;
        rips_kernel_sc0<<<grid, block, 0, stream>>>(p16, verts0, verts1, out, e0, e1);
    } else {
        int total = 2 * e1 + e0;
        int block = 256;
        int grid = (total + block - 1) / block;
        rips_kernel_f2<<<grid, block, 0, stream>>>(points, verts0, verts1, out, e0, e1);
    }
}